// Round 1
// baseline (7815.669 us; speedup 1.0000x reference)
//
#include <hip/hip_runtime.h>
#include <hip/hip_bf16.h>

// HMM forward (batched, log-space) on MI355X.
// Strategy: linear-space scaled forward algorithm.
//   carry v[k] (sum-normalized, f32, in LDS) and scalar L = log-scale.
//   per step: acc[j] = sum_k A[j,k]*v[k]  (A = softmax(trans, axis=0), bf16)
//             w[j] = exp(em_t[j]) * acc[j];  S = sum_j w;  L += log S;  v = w/S
//   per-step logsumexp(la_t) == L after update -> output at t = T[b]-1.
// Precompute: emitT (log_softmax(emit,1) transposed, f32), A packed bf16x4
// k-major (uint2 per 4 k's per j), log_pi.

#define N_ST 512
#define VOCAB 10000
#define BATCH 64
#define T_MAX 1024

// ---------------- workspace layout (bytes) ----------------
#define WS_EMITT   0                         // 10000*512 f32 = 20,480,000
#define WS_A4      20480000                  // 128*512 uint2 = 524,288
#define WS_ROWLSE  21004288                  // 512 f32
#define WS_COLLSE  21006336                  // 512 f32
#define WS_LOGPI   21008384                  // 512 f32
// total ~21.0 MB

static __device__ __forceinline__ unsigned short f32_to_bf16_rne(float f) {
    unsigned u = __float_as_uint(f);
    unsigned rounding = 0x7fffu + ((u >> 16) & 1u);
    return (unsigned short)((u + rounding) >> 16);
}

// ---- rowLSE[n] = logsumexp_m emit[n, m]  (512 blocks x 256 thr) ----
__global__ __launch_bounds__(256) void k_row_lse(const float* __restrict__ emit,
                                                 float* __restrict__ rowLSE) {
    const int n = blockIdx.x;
    const float* row = emit + (size_t)n * VOCAB;
    __shared__ float redm[4], reds[4];
    const int tid = threadIdx.x, lane = tid & 63, wid = tid >> 6;

    float m = -INFINITY;
    for (int i = tid; i < VOCAB; i += 256) m = fmaxf(m, row[i]);
    #pragma unroll
    for (int o = 32; o; o >>= 1) m = fmaxf(m, __shfl_down(m, o));
    if (lane == 0) redm[wid] = m;
    __syncthreads();
    if (tid == 0) {
        float r = redm[0];
        for (int i = 1; i < 4; ++i) r = fmaxf(r, redm[i]);
        redm[0] = r;
    }
    __syncthreads();
    m = redm[0];

    float s = 0.f;
    for (int i = tid; i < VOCAB; i += 256) s += __expf(row[i] - m);
    #pragma unroll
    for (int o = 32; o; o >>= 1) s += __shfl_down(s, o);
    if (lane == 0) reds[wid] = s;
    __syncthreads();
    if (tid == 0) {
        float r = reds[0] + reds[1] + reds[2] + reds[3];
        rowLSE[n] = m + __logf(r);
    }
}

// ---- emitT[m*512+n] = emit[n*VOCAB+m] - rowLSE[n] ----
__global__ __launch_bounds__(256) void k_emitT(const float* __restrict__ emit,
                                               const float* __restrict__ rowLSE,
                                               float* __restrict__ emitT) {
    const size_t gid = (size_t)blockIdx.x * 256 + threadIdx.x;  // < 10000*512
    const int m = (int)(gid >> 9);
    const int n = (int)(gid & 511);
    emitT[gid] = emit[(size_t)n * VOCAB + m] - rowLSE[n];
}

// ---- colLSE[k] = logsumexp_j trans[j, k]  (512 blocks x 256 thr) ----
__global__ __launch_bounds__(256) void k_col_lse(const float* __restrict__ trans,
                                                 float* __restrict__ colLSE) {
    const int k = blockIdx.x;
    const int tid = threadIdx.x, lane = tid & 63, wid = tid >> 6;
    __shared__ float redm[4], reds[4];

    float a = trans[(size_t)tid * N_ST + k];
    float b = trans[(size_t)(tid + 256) * N_ST + k];
    float m = fmaxf(a, b);
    #pragma unroll
    for (int o = 32; o; o >>= 1) m = fmaxf(m, __shfl_down(m, o));
    if (lane == 0) redm[wid] = m;
    __syncthreads();
    if (tid == 0) {
        float r = fmaxf(fmaxf(redm[0], redm[1]), fmaxf(redm[2], redm[3]));
        redm[0] = r;
    }
    __syncthreads();
    m = redm[0];

    float s = __expf(a - m) + __expf(b - m);
    #pragma unroll
    for (int o = 32; o; o >>= 1) s += __shfl_down(s, o);
    if (lane == 0) reds[wid] = s;
    __syncthreads();
    if (tid == 0) colLSE[k] = m + __logf(reds[0] + reds[1] + reds[2] + reds[3]);
}

// ---- A4[k4*512 + j] = bf16x4{ exp(trans[j, 4k4+i] - colLSE[4k4+i]) } ----
// (column-normalized transition matrix, k-major packing of 4 consecutive k)
__global__ __launch_bounds__(512) void k_packA(const float* __restrict__ trans,
                                               const float* __restrict__ colLSE,
                                               uint2* __restrict__ A4) {
    const int k4 = blockIdx.x;   // 0..127
    const int j  = threadIdx.x;  // 0..511
    const int k0 = 4 * k4;
    float a0 = __expf(trans[(size_t)j * N_ST + k0 + 0] - colLSE[k0 + 0]);
    float a1 = __expf(trans[(size_t)j * N_ST + k0 + 1] - colLSE[k0 + 1]);
    float a2 = __expf(trans[(size_t)j * N_ST + k0 + 2] - colLSE[k0 + 2]);
    float a3 = __expf(trans[(size_t)j * N_ST + k0 + 3] - colLSE[k0 + 3]);
    uint2 p;
    p.x = (unsigned)f32_to_bf16_rne(a0) | ((unsigned)f32_to_bf16_rne(a1) << 16);
    p.y = (unsigned)f32_to_bf16_rne(a2) | ((unsigned)f32_to_bf16_rne(a3) << 16);
    A4[(size_t)k4 * N_ST + j] = p;
}

// ---- logpi[j] = priors[j] - LSE(priors) ----
__global__ __launch_bounds__(512) void k_logpi(const float* __restrict__ priors,
                                               float* __restrict__ logpi) {
    const int j = threadIdx.x, lane = j & 63, wid = j >> 6;
    __shared__ float redm[8], reds[8], bcast;
    float v = priors[j];

    float m = v;
    #pragma unroll
    for (int o = 32; o; o >>= 1) m = fmaxf(m, __shfl_down(m, o));
    if (lane == 0) redm[wid] = m;
    __syncthreads();
    if (j == 0) {
        float r = redm[0];
        for (int i = 1; i < 8; ++i) r = fmaxf(r, redm[i]);
        redm[0] = r;
    }
    __syncthreads();
    m = redm[0];

    float s = __expf(v - m);
    #pragma unroll
    for (int o = 32; o; o >>= 1) s += __shfl_down(s, o);
    if (lane == 0) reds[wid] = s;
    __syncthreads();
    if (j == 0) {
        float r = 0.f;
        for (int i = 0; i < 8; ++i) r += reds[i];
        bcast = m + __logf(r);
    }
    __syncthreads();
    logpi[j] = v - bcast;
}

// ---- main: one workgroup per chain b; thread j owns state j ----
__global__ __launch_bounds__(512) void hmm_main(const int* __restrict__ x,
                                                const int* __restrict__ T,
                                                const float* __restrict__ emitT,
                                                const uint2* __restrict__ A4,
                                                const float* __restrict__ logpi,
                                                float* __restrict__ out) {
    __shared__ __align__(16) float vbuf[N_ST];
    __shared__ float red[9];
    const int b = blockIdx.x;
    const int j = threadIdx.x;
    const int lane = j & 63, wid = j >> 6;

    int Tb = T[b];
    Tb = Tb < 1 ? 1 : (Tb > T_MAX ? T_MAX : Tb);
    const int* xb = x + (size_t)b * T_MAX;

    // ---- t = 0 ----
    const int x0 = xb[0];
    float la0 = emitT[(size_t)x0 * N_ST + j] + logpi[j];
    float w = __expf(la0);

    float s = w;
    #pragma unroll
    for (int o = 32; o; o >>= 1) s += __shfl_down(s, o);
    if (lane == 0) red[wid] = s;
    __syncthreads();
    if (j == 0) {
        float r = 0.f;
        for (int i = 0; i < 8; ++i) r += red[i];
        red[8] = r;
    }
    __syncthreads();
    float S = red[8];
    float L = __logf(S);
    if (Tb == 1) {
        if (j == 0) out[b] = L;
        return;
    }
    __syncthreads();                 // all threads read red[8] before reuse
    vbuf[j] = w * (1.0f / S);
    __syncthreads();

    const float4* vp4 = reinterpret_cast<const float4*>(vbuf);

    // ---- t = 1 .. Tb-1 ----
    for (int t = 1; t < Tb; ++t) {
        const int xt = xb[t];
        const float e = emitT[(size_t)xt * N_ST + j];

        float acc = 0.f;
        #pragma unroll 4
        for (int k4 = 0; k4 < N_ST / 4; ++k4) {
            uint2 a = A4[(size_t)k4 * N_ST + j];
            float4 vv = vp4[k4];
            float a0 = __uint_as_float(a.x << 16);
            float a1 = __uint_as_float(a.x & 0xffff0000u);
            float a2 = __uint_as_float(a.y << 16);
            float a3 = __uint_as_float(a.y & 0xffff0000u);
            acc = fmaf(a0, vv.x, acc);
            acc = fmaf(a1, vv.y, acc);
            acc = fmaf(a2, vv.z, acc);
            acc = fmaf(a3, vv.w, acc);
        }

        float w2 = __expf(e) * acc;

        float s2 = w2;
        #pragma unroll
        for (int o = 32; o; o >>= 1) s2 += __shfl_down(s2, o);
        if (lane == 0) red[wid] = s2;   // safe: prior red[8] consumers passed barrier
        __syncthreads();                // also guarantees all k-loop vbuf reads done
        if (j == 0) {
            float r = 0.f;
            for (int i = 0; i < 8; ++i) r += red[i];
            red[8] = r;
        }
        __syncthreads();
        const float St = red[8];
        L += __logf(St);

        if (t == Tb - 1) {
            if (j == 0) out[b] = L;
            break;                      // uniform across block
        }
        __syncthreads();                // all threads consumed red[8]
        vbuf[j] = w2 * (1.0f / St);     // distinct slots; k-loop reads already done
        __syncthreads();
    }
}

extern "C" void kernel_launch(void* const* d_in, const int* in_sizes, int n_in,
                              void* d_out, int out_size, void* d_ws, size_t ws_size,
                              hipStream_t stream) {
    const int*   x      = (const int*)d_in[0];     // (64, 1024)
    const int*   T      = (const int*)d_in[1];     // (64,)
    const float* priors = (const float*)d_in[2];   // (512,)
    const float* trans  = (const float*)d_in[3];   // (512, 512)
    const float* emit   = (const float*)d_in[4];   // (512, 10000)
    float* out = (float*)d_out;                    // (64, 1)

    char* ws = (char*)d_ws;
    float* emitT  = (float*)(ws + WS_EMITT);
    uint2* A4     = (uint2*)(ws + WS_A4);
    float* rowLSE = (float*)(ws + WS_ROWLSE);
    float* colLSE = (float*)(ws + WS_COLLSE);
    float* logpi  = (float*)(ws + WS_LOGPI);

    k_row_lse<<<N_ST, 256, 0, stream>>>(emit, rowLSE);
    k_emitT<<<(VOCAB * N_ST) / 256, 256, 0, stream>>>(emit, rowLSE, emitT);
    k_col_lse<<<N_ST, 256, 0, stream>>>(trans, colLSE);
    k_packA<<<N_ST / 4, 512, 0, stream>>>(trans, colLSE, A4);
    k_logpi<<<1, 512, 0, stream>>>(priors, logpi);

    hmm_main<<<BATCH, 512, 0, stream>>>(x, T, emitT, A4, logpi, out);
}

// Round 3
// 1745.208 us; speedup vs baseline: 4.4784x; 4.4784x over previous
//
#include <hip/hip_runtime.h>
#include <hip/hip_bf16.h>

// HMM forward on MI355X — fp8 register-resident MFMA version.
// Linear-space scaled forward: carry v (sum-normalized, x256, fp8 in LDS) + scalar L.
// Per step: acc = Afp8 * v via mfma_f32_16x16x32_fp8_fp8 (A resident in VGPRs),
//           w = E * acc (E = softmax-emission, f32, precomputed), S = sum w,
//           L += log S - 16 ln2, v = 256 w / S.
// A-frag (16x16x32 fp8): lane l holds A[j0+(l&15)][k0+(l>>4)*8+i], i=0..7 (i64).
// B-frag: lane l holds B[k0+(l>>4)*8+i][col=l&15]; all 16 cols = v -> ds_read_b64.
// D-frag: col=l&15, row=(l>>4)*4+r (verified dtype-independent).

typedef unsigned long long u64;
typedef unsigned int u32;
using f32x4 = __attribute__((ext_vector_type(4))) float;

#define N_ST 512
#define VOCAB 10000
#define BATCH 64
#define T_MAX 1024

// ---------------- workspace layout (bytes) ----------------
#define WS_EXPEMITT 0          // 10000*512 f32 = 20,480,000
#define WS_A8       20480000   // 512 frags * 512 B = 262,144 (fp8 packed fragments)
#define WS_ROWLSE   20742144   // 512 f32
#define WS_COLLSE   20744192   // 512 f32
#define WS_PINORM   20746240   // 512 f32
// total 20,748,288 bytes

// ---- software OCP e4m3fn encoder (RNE, saturating), fallback only ----
static __device__ __forceinline__ u32 enc_e4m3(float f) {
    if (!(f > 0.f)) return 0u;                       // zero / negative / nan -> 0
    unsigned u = __float_as_uint(f);
    int e = (int)((u >> 23) & 0xff) - 127;
    unsigned m = u & 0x7fffffu;
    if (e > 8 || (e == 8 && m >= 0x700000u)) return 0x7eu;   // clamp to 448
    if (e >= -6) {
        unsigned mant = m >> 20;
        unsigned rest = m & 0xfffffu;
        if (rest > 0x80000u || (rest == 0x80000u && (mant & 1u))) mant++;
        unsigned r = ((unsigned)(e + 7) << 3) + mant;        // carry into exp ok
        return r > 0x7eu ? 0x7eu : r;
    }
    if (e < -10) return 0u;
    unsigned full = 0x800000u | m;
    int shift = 23 - (e + 9);
    unsigned r = full >> shift;
    unsigned rem = full & ((1u << shift) - 1u);
    unsigned half = 1u << (shift - 1);
    if (rem > half || (rem == half && (r & 1u))) r++;
    return r;
}

template <bool HI>
static __device__ __forceinline__ u32 cvtpk2(float a, float b, u32 old) {
#if __has_builtin(__builtin_amdgcn_cvt_pk_fp8_f32)
    return (u32)__builtin_amdgcn_cvt_pk_fp8_f32(a, b, (int)old, HI);
#else
    unsigned v = enc_e4m3(a) | (enc_e4m3(b) << 8);
    return HI ? ((old & 0x0000ffffu) | (v << 16)) : ((old & 0xffff0000u) | v);
#endif
}

// ---- rowLSE[n] = logsumexp_m emit[n, m] ----
__global__ __launch_bounds__(256) void k_row_lse(const float* __restrict__ emit,
                                                 float* __restrict__ rowLSE) {
    const int n = blockIdx.x;
    const float* row = emit + (size_t)n * VOCAB;
    __shared__ float redm[4], reds[4];
    const int tid = threadIdx.x, lane = tid & 63, wid = tid >> 6;

    float m = -INFINITY;
    for (int i = tid; i < VOCAB; i += 256) m = fmaxf(m, row[i]);
    #pragma unroll
    for (int o = 32; o; o >>= 1) m = fmaxf(m, __shfl_down(m, o));
    if (lane == 0) redm[wid] = m;
    __syncthreads();
    if (tid == 0) {
        float r = fmaxf(fmaxf(redm[0], redm[1]), fmaxf(redm[2], redm[3]));
        redm[0] = r;
    }
    __syncthreads();
    m = redm[0];

    float s = 0.f;
    for (int i = tid; i < VOCAB; i += 256) s += __expf(row[i] - m);
    #pragma unroll
    for (int o = 32; o; o >>= 1) s += __shfl_down(s, o);
    if (lane == 0) reds[wid] = s;
    __syncthreads();
    if (tid == 0) rowLSE[n] = m + __logf(reds[0] + reds[1] + reds[2] + reds[3]);
}

// ---- expEmitT[m*512+n] = exp(emit[n,m] - rowLSE[n])  (softmax, transposed) ----
__global__ __launch_bounds__(256) void k_expEmitT(const float* __restrict__ emit,
                                                  const float* __restrict__ rowLSE,
                                                  float* __restrict__ expEmitT) {
    const size_t gid = (size_t)blockIdx.x * 256 + threadIdx.x;  // < 10000*512
    const int m = (int)(gid >> 9);
    const int n = (int)(gid & 511);
    expEmitT[gid] = __expf(emit[(size_t)n * VOCAB + m] - rowLSE[n]);
}

// ---- colLSE[k] = logsumexp_j trans[j, k] ----
__global__ __launch_bounds__(256) void k_col_lse(const float* __restrict__ trans,
                                                 float* __restrict__ colLSE) {
    const int k = blockIdx.x;
    const int tid = threadIdx.x, lane = tid & 63, wid = tid >> 6;
    __shared__ float redm[4], reds[4];

    float a = trans[(size_t)tid * N_ST + k];
    float b = trans[(size_t)(tid + 256) * N_ST + k];
    float m = fmaxf(a, b);
    #pragma unroll
    for (int o = 32; o; o >>= 1) m = fmaxf(m, __shfl_down(m, o));
    if (lane == 0) redm[wid] = m;
    __syncthreads();
    if (tid == 0) redm[0] = fmaxf(fmaxf(redm[0], redm[1]), fmaxf(redm[2], redm[3]));
    __syncthreads();
    m = redm[0];

    float s = __expf(a - m) + __expf(b - m);
    #pragma unroll
    for (int o = 32; o; o >>= 1) s += __shfl_down(s, o);
    if (lane == 0) reds[wid] = s;
    __syncthreads();
    if (tid == 0) colLSE[k] = m + __logf(reds[0] + reds[1] + reds[2] + reds[3]);
}

// ---- pack A into fp8 MFMA A-fragments, scaled x256 ----
// frag f = w*64 + ks*4 + jt  (w=wave, ks=k-slice of 32, jt=j-tile of 16)
// lane l, byte i: A8[f*512 + l*8 + i] = fp8(256*exp(trans[j,k]-colLSE[k]))
//   with j = w*64 + jt*16 + (l&15),  k = ks*32 + (l>>4)*8 + i
__global__ __launch_bounds__(64) void k_packA_fp8(const float* __restrict__ trans,
                                                  const float* __restrict__ colLSE,
                                                  u64* __restrict__ A8) {
    const int f = blockIdx.x;        // 0..511
    const int l = threadIdx.x;       // 0..63
    const int w = f >> 6, ks = (f >> 2) & 15, jt = f & 3;
    const int j = w * 64 + jt * 16 + (l & 15);
    const int k0 = ks * 32 + (l >> 4) * 8;
    float v[8];
    #pragma unroll
    for (int i = 0; i < 8; ++i)
        v[i] = 256.0f * __expf(trans[(size_t)j * N_ST + k0 + i] - colLSE[k0 + i]);
    u32 lo = cvtpk2<false>(v[0], v[1], 0u);
    lo = cvtpk2<true>(v[2], v[3], lo);
    u32 hi = cvtpk2<false>(v[4], v[5], 0u);
    hi = cvtpk2<true>(v[6], v[7], hi);
    A8[(size_t)f * 64 + l] = (u64)lo | ((u64)hi << 32);
}

// ---- pinorm[j] = softmax(priors)[j] ----
__global__ __launch_bounds__(512) void k_pinorm(const float* __restrict__ priors,
                                                float* __restrict__ pinorm) {
    const int j = threadIdx.x, lane = j & 63, wid = j >> 6;
    __shared__ float redm[8], reds[8];
    float v = priors[j];

    float m = v;
    #pragma unroll
    for (int o = 32; o; o >>= 1) m = fmaxf(m, __shfl_down(m, o));
    if (lane == 0) redm[wid] = m;
    __syncthreads();
    if (j == 0) {
        float r = redm[0];
        for (int i = 1; i < 8; ++i) r = fmaxf(r, redm[i]);
        redm[0] = r;
    }
    __syncthreads();
    m = redm[0];

    float s = __expf(v - m);
    #pragma unroll
    for (int o = 32; o; o >>= 1) s += __shfl_down(s, o);
    if (lane == 0) reds[wid] = s;
    __syncthreads();
    if (j == 0) {
        float r = 0.f;
        for (int i = 0; i < 8; ++i) r += reds[i];
        reds[0] = r;
    }
    __syncthreads();
    pinorm[j] = __expf(v - m) / reds[0];
}

// ---- main: one WG per chain; 8 waves x 64 states; A resident in VGPRs ----
__global__ __launch_bounds__(512, 2) void hmm_main(const int* __restrict__ x,
                                                   const int* __restrict__ T,
                                                   const float* __restrict__ expEmitT,
                                                   const u64* __restrict__ A8,
                                                   const float* __restrict__ pinorm,
                                                   float* __restrict__ out) {
    __shared__ u64 vq[64];        // fp8 v (x256 scale), 512 B
    __shared__ float red[8];
    const int b = blockIdx.x;
    const int tid = threadIdx.x;
    const int l = tid & 63;
    const int wid = tid >> 6;
    const int grp = l >> 4;           // k-group / D-row-group
    const int wbase = wid * 64;
    const int rbase = grp * 4;        // row base within 16x16 tile

    int Tb = T[b];
    Tb = Tb < 1 ? 1 : (Tb > T_MAX ? T_MAX : Tb);
    const int* xb = x + (size_t)b * T_MAX;

    // ---- load resident A fragments: 64 x u64 per thread (128 VGPRs) ----
    u64 af[64];
    const u64* ap = A8 + (size_t)wid * 4096 + l;
    #pragma unroll
    for (int i = 0; i < 64; ++i) af[i] = ap[(size_t)i * 64];

    // ---- t = 0 ----
    const int x0 = xb[0];
    const float* e0row = expEmitT + (size_t)x0 * N_ST;
    float wv[16];
    float s = 0.f;
    #pragma unroll
    for (int jt = 0; jt < 4; ++jt) {
        #pragma unroll
        for (int r = 0; r < 4; ++r) {
            const int j = wbase + jt * 16 + rbase + r;
            float t0 = e0row[j] * pinorm[j];
            wv[jt * 4 + r] = t0;
            s += t0;
        }
    }
    s += __shfl_xor(s, 16);
    s += __shfl_xor(s, 32);
    if (l == 0) red[wid] = s;
    __syncthreads();
    float S = red[0] + red[1] + red[2] + red[3] + red[4] + red[5] + red[6] + red[7];
    float L = logf(S);
    if (Tb == 1) {
        if (tid == 0) out[b] = L;
        return;
    }
    {
        const float sc = 256.0f / S;
        if ((l & 15) == 0) {
            u32* vw = (u32*)vq;
            #pragma unroll
            for (int jt = 0; jt < 4; ++jt) {
                u32 pk = cvtpk2<false>(wv[jt * 4 + 0] * sc, wv[jt * 4 + 1] * sc, 0u);
                pk = cvtpk2<true>(wv[jt * 4 + 2] * sc, wv[jt * 4 + 3] * sc, pk);
                vw[(wbase >> 2) + jt * 4 + grp] = pk;
            }
        }
    }
    __syncthreads();

    // ---- t = 1 .. Tb-1 ----
    int xt = xb[1];
    for (int t = 1;; ++t) {
        // issue emission loads early (covered by MFMAs; L3-resident rows)
        const float* erow = expEmitT + (size_t)xt * N_ST;
        float ev[16];
        #pragma unroll
        for (int jt = 0; jt < 4; ++jt) {
            #pragma unroll
            for (int r = 0; r < 4; ++r)
                ev[jt * 4 + r] = erow[wbase + jt * 16 + rbase + r];
        }
        int tn = t + 1;
        if (tn > T_MAX - 1) tn = T_MAX - 1;
        const int xn = xb[tn];

        // 64 MFMAs: 4 j-tiles x 16 k-slices, B = v replicated over 16 cols
        f32x4 acc0 = {0.f, 0.f, 0.f, 0.f};
        f32x4 acc1 = {0.f, 0.f, 0.f, 0.f};
        f32x4 acc2 = {0.f, 0.f, 0.f, 0.f};
        f32x4 acc3 = {0.f, 0.f, 0.f, 0.f};
        #pragma unroll
        for (int ks = 0; ks < 16; ++ks) {
            const long bq = (long)vq[ks * 4 + grp];
            acc0 = __builtin_amdgcn_mfma_f32_16x16x32_fp8_fp8((long)af[ks * 4 + 0], bq, acc0, 0, 0, 0);
            acc1 = __builtin_amdgcn_mfma_f32_16x16x32_fp8_fp8((long)af[ks * 4 + 1], bq, acc1, 0, 0, 0);
            acc2 = __builtin_amdgcn_mfma_f32_16x16x32_fp8_fp8((long)af[ks * 4 + 2], bq, acc2, 0, 0, 0);
            acc3 = __builtin_amdgcn_mfma_f32_16x16x32_fp8_fp8((long)af[ks * 4 + 3], bq, acc3, 0, 0, 0);
        }

        // epilogue: w = E*acc, reduce S over 512 states
        float wv2[16];
        float s2 = 0.f;
        #pragma unroll
        for (int r = 0; r < 4; ++r) { wv2[0 + r]  = ev[0 + r]  * acc0[r]; s2 += wv2[0 + r]; }
        #pragma unroll
        for (int r = 0; r < 4; ++r) { wv2[4 + r]  = ev[4 + r]  * acc1[r]; s2 += wv2[4 + r]; }
        #pragma unroll
        for (int r = 0; r < 4; ++r) { wv2[8 + r]  = ev[8 + r]  * acc2[r]; s2 += wv2[8 + r]; }
        #pragma unroll
        for (int r = 0; r < 4; ++r) { wv2[12 + r] = ev[12 + r] * acc3[r]; s2 += wv2[12 + r]; }
        s2 += __shfl_xor(s2, 16);
        s2 += __shfl_xor(s2, 32);
        if (l == 0) red[wid] = s2;
        __syncthreads();
        const float St = red[0] + red[1] + red[2] + red[3] +
                         red[4] + red[5] + red[6] + red[7];
        L += logf(St) - 11.090354888959125f;   // log S~ - 16 ln2 (A,v each x256)
        if (t == Tb - 1) break;

        const float sc = 256.0f / St;
        if ((l & 15) == 0) {
            u32* vw = (u32*)vq;
            #pragma unroll
            for (int jt = 0; jt < 4; ++jt) {
                u32 pk = cvtpk2<false>(wv2[jt * 4 + 0] * sc, wv2[jt * 4 + 1] * sc, 0u);
                pk = cvtpk2<true>(wv2[jt * 4 + 2] * sc, wv2[jt * 4 + 3] * sc, pk);
                vw[(wbase >> 2) + jt * 4 + grp] = pk;
            }
        }
        __syncthreads();
        xt = xn;
    }
    if (tid == 0) out[b] = L;
}

extern "C" void kernel_launch(void* const* d_in, const int* in_sizes, int n_in,
                              void* d_out, int out_size, void* d_ws, size_t ws_size,
                              hipStream_t stream) {
    const int*   x      = (const int*)d_in[0];     // (64, 1024)
    const int*   T      = (const int*)d_in[1];     // (64,)
    const float* priors = (const float*)d_in[2];   // (512,)
    const float* trans  = (const float*)d_in[3];   // (512, 512)
    const float* emit   = (const float*)d_in[4];   // (512, 10000)
    float* out = (float*)d_out;                    // (64, 1)

    char* ws = (char*)d_ws;
    float* expEmitT = (float*)(ws + WS_EXPEMITT);
    u64*   A8       = (u64*)(ws + WS_A8);
    float* rowLSE   = (float*)(ws + WS_ROWLSE);
    float* colLSE   = (float*)(ws + WS_COLLSE);
    float* pinorm   = (float*)(ws + WS_PINORM);

    k_row_lse<<<N_ST, 256, 0, stream>>>(emit, rowLSE);
    k_expEmitT<<<(VOCAB * N_ST) / 256, 256, 0, stream>>>(emit, rowLSE, expEmitT);
    k_col_lse<<<N_ST, 256, 0, stream>>>(trans, colLSE);
    k_packA_fp8<<<N_ST, 64, 0, stream>>>(trans, colLSE, A8);
    k_pinorm<<<1, 512, 0, stream>>>(priors, pinorm);

    hmm_main<<<BATCH, 512, 0, stream>>>(x, T, expEmitT, A8, pinorm, out);
}